// Round 1
// baseline (845.318 us; speedup 1.0000x reference)
//
#include <hip/hip_runtime.h>
#include <hip/hip_bf16.h>
#include <math.h>

typedef __attribute__((ext_vector_type(8))) short short8;   // 8 x bf16 (MFMA frag)
typedef __attribute__((ext_vector_type(4))) float floatx4;  // MFMA accumulator

__device__ __forceinline__ ushort f2bf(float f) {
  __hip_bfloat16 h = __float2bfloat16(f);
  return *reinterpret_cast<ushort*>(&h);
}
__device__ __forceinline__ float bf2f(ushort u) {
  union { unsigned int i; float f; } c; c.i = ((unsigned)u) << 16; return c.f;
}

// async global->LDS 16B DMA (dest = wave-uniform base + lane*16)
__device__ __forceinline__ void lds_dma16(const void* g, void* l) {
  __builtin_amdgcn_global_load_lds((const __attribute__((address_space(1))) void*)g,
                                   (__attribute__((address_space(3))) void*)l, 16, 0, 0);
}

// ---------- fused fp32 -> bf16 conversion for all four weights ----------
__global__ __launch_bounds__(256) void cvt_all(const float* __restrict__ p0, ushort* __restrict__ o0, int b0,
                                               const float* __restrict__ p1, ushort* __restrict__ o1, int b1,
                                               const float* __restrict__ p2, ushort* __restrict__ o2, int b2,
                                               const float* __restrict__ p3, ushort* __restrict__ o3) {
  int b = blockIdx.x;
  const float* in; ushort* out; int base;
  if (b < b0)            { in = p0; out = o0; base = 0; }
  else if (b < b0 + b1)  { in = p1; out = o1; base = b0; }
  else if (b < b0 + b1 + b2) { in = p2; out = o2; base = b0 + b1; }
  else                   { in = p3; out = o3; base = b0 + b1 + b2; }
  int i = (b - base) * 256 + threadIdx.x;
  float4 v = ((const float4*)in)[i];
  ushort4 o;
  o.x = f2bf(v.x); o.y = f2bf(v.y); o.z = f2bf(v.z); o.w = f2bf(v.w);
  ((ushort4*)out)[i] = o;
}

// ---------- RMSNorm fp32 -> bf16 ----------
__global__ __launch_bounds__(256) void rmsnorm_f32(const float* __restrict__ x,
                                                   const float* __restrict__ gamma,
                                                   ushort* __restrict__ y, int D, float sqrtD) {
  const int row = blockIdx.x;
  const float* xr = x + (size_t)row * D;
  float ss = 0.f;
  for (int i = threadIdx.x * 4; i < D; i += 1024) {
    float4 v = *(const float4*)&xr[i];
    ss += v.x * v.x + v.y * v.y + v.z * v.z + v.w * v.w;
  }
#pragma unroll
  for (int off = 1; off < 64; off <<= 1) ss += __shfl_xor(ss, off);
  __shared__ float red[4];
  if ((threadIdx.x & 63) == 0) red[threadIdx.x >> 6] = ss;
  __syncthreads();
  ss = red[0] + red[1] + red[2] + red[3];
  const float sc = sqrtD / fmaxf(sqrtf(ss), 1e-12f);
  for (int i = threadIdx.x * 4; i < D; i += 1024) {
    float4 v = *(const float4*)&xr[i];
    ushort4 o;
    o.x = f2bf(v.x * sc * gamma[i]);
    o.y = f2bf(v.y * sc * gamma[i + 1]);
    o.z = f2bf(v.z * sc * gamma[i + 2]);
    o.w = f2bf(v.w * sc * gamma[i + 3]);
    *(ushort4*)&y[(size_t)row * D + i] = o;
  }
}

// ---------- RMSNorm bf16 -> bf16 ----------
__global__ __launch_bounds__(256) void rmsnorm_bf16(const ushort* __restrict__ x,
                                                    const float* __restrict__ gamma,
                                                    ushort* __restrict__ y, int D, float sqrtD) {
  const int row = blockIdx.x;
  const ushort* xr = x + (size_t)row * D;
  float ss = 0.f;
  for (int i = threadIdx.x * 8; i < D; i += 2048) {
    short8 v = *(const short8*)&xr[i];
#pragma unroll
    for (int e = 0; e < 8; e++) { float f = bf2f((ushort)v[e]); ss += f * f; }
  }
#pragma unroll
  for (int off = 1; off < 64; off <<= 1) ss += __shfl_xor(ss, off);
  __shared__ float red[4];
  if ((threadIdx.x & 63) == 0) red[threadIdx.x >> 6] = ss;
  __syncthreads();
  ss = red[0] + red[1] + red[2] + red[3];
  const float sc = sqrtD / fmaxf(sqrtf(ss), 1e-12f);
  for (int i = threadIdx.x * 8; i < D; i += 2048) {
    short8 v = *(const short8*)&xr[i];
    short8 ov;
#pragma unroll
    for (int e = 0; e < 8; e++) ov[e] = (short)f2bf(bf2f((ushort)v[e]) * sc * gamma[i + e]);
    *(short8*)&y[(size_t)row * D + i] = ov;
  }
}

// ---------- GEMM v3: 128x128 tile, BK=64, global_load_lds + XOR swizzle ----------
template <int EPI, int ACT, int OUTBF16>
__global__ __launch_bounds__(256, 3) void gemm3(const ushort* __restrict__ A,
                                                const ushort* __restrict__ B,
                                                const float* __restrict__ bias,
                                                const float* __restrict__ bias2,
                                                void* __restrict__ C1,
                                                void* __restrict__ C2,
                                                int M, int N, int K, int Ksplit, float scale) {
  __shared__ ushort As[128 * 64];
  __shared__ ushort Bs[128 * 64];
  const int tid = threadIdx.x;
  const int wave = tid >> 6;
  const int lane = tid & 63;
  const int c16 = lane & 15;
  const int quad = lane >> 4;
  const int wm = wave >> 1;
  const int wn = wave & 1;
  const size_t m0 = (size_t)blockIdx.x * 128;
  const size_t n0 = (size_t)blockIdx.y * 128;
  const int kbeg = blockIdx.z * Ksplit;
  const int kend = kbeg + Ksplit;

  const int rsub = lane >> 3;
  const int csw = (lane & 7) ^ rsub;

  const floatx4 zero = {0.f, 0.f, 0.f, 0.f};
  floatx4 acc[4][4];
#pragma unroll
  for (int a = 0; a < 4; a++)
#pragma unroll
    for (int b = 0; b < 4; b++) acc[a][b] = zero;

  for (int k0 = kbeg; k0 < kend; k0 += 64) {
    __syncthreads();
#pragma unroll
    for (int i = 0; i < 4; i++) {
      const int j = wave * 4 + i;
      const int r = j * 8 + rsub;
      lds_dma16(&A[(m0 + r) * K + k0 + csw * 8], (void*)(As + j * 512));
      lds_dma16(&B[(n0 + r) * K + k0 + csw * 8], (void*)(Bs + j * 512));
    }
    __syncthreads();
#pragma unroll
    for (int kc = 0; kc < 2; kc++) {
      short8 af[4], bf4[4];
#pragma unroll
      for (int mt = 0; mt < 4; mt++) {
        const int row = wm * 64 + mt * 16 + c16;
        af[mt] = *(const short8*)&As[row * 64 + (((kc * 4 + quad) ^ (row & 7)) << 3)];
      }
#pragma unroll
      for (int nt = 0; nt < 4; nt++) {
        const int row = wn * 64 + nt * 16 + c16;
        bf4[nt] = *(const short8*)&Bs[row * 64 + (((kc * 4 + quad) ^ (row & 7)) << 3)];
      }
#pragma unroll
      for (int mt = 0; mt < 4; mt++)
#pragma unroll
        for (int nt = 0; nt < 4; nt++)
          acc[mt][nt] = __builtin_amdgcn_mfma_f32_16x16x32_bf16(af[mt], bf4[nt], acc[mt][nt], 0, 0, 0);
    }
  }

#pragma unroll
  for (int mt = 0; mt < 4; mt++) {
#pragma unroll
    for (int nt = 0; nt < 4; nt++) {
      const size_t col = n0 + wn * 64 + nt * 16 + c16;
      const size_t row0 = m0 + wm * 64 + mt * 16 + quad * 4;
      if (EPI == 0) {
        const float bv = bias[col];
#pragma unroll
        for (int r = 0; r < 4; r++) {
          float v = acc[mt][nt][r] + bv;
          if (ACT) v = v / (1.f + __expf(-v));
          if (OUTBF16) ((ushort*)C1)[(row0 + r) * N + col] = f2bf(v);
          else         ((float*)C1)[(row0 + r) * N + col] = v;
        }
      } else if (EPI == 1) {
        float* plane = (float*)C1 + (size_t)blockIdx.z * M * N;
#pragma unroll
        for (int r = 0; r < 4; r++)
          plane[(row0 + r) * N + col] = acc[mt][nt][r];
      } else {
        if (col < 16384) {
          const float bv = bias[col];
#pragma unroll
          for (int r = 0; r < 4; r++)
            ((ushort*)C1)[(row0 + r) * 16384 + col] = f2bf((acc[mt][nt][r] + bv) * scale);
        } else {
          const size_t ckv = col - 16384;
          const float bv = bias2[ckv];
#pragma unroll
          for (int r = 0; r < 4; r++)
            ((ushort*)C2)[(row0 + r) * 2048 + ckv] = f2bf(acc[mt][nt][r] + bv);
        }
      }
    }
  }
}

// ---------- split-K reduce + bias + SiLU epilogue ----------
template <int NZ, int OUTBF16>
__global__ __launch_bounds__(256) void epi_sum_silu(const float* __restrict__ accb,
                                                    const float* __restrict__ bias,
                                                    void* __restrict__ outp, int N, int n4,
                                                    size_t plane4) {
  int i = blockIdx.x * 256 + threadIdx.x;
  if (i >= n4) return;
  float4 v = ((const float4*)accb)[i];
#pragma unroll
  for (int z = 1; z < NZ; z++) {
    float4 p = ((const float4*)accb)[i + z * plane4];
    v.x += p.x; v.y += p.y; v.z += p.z; v.w += p.w;
  }
  const float4 b = *(const float4*)&bias[(i * 4) % N];
  v.x += b.x; v.y += b.y; v.z += b.z; v.w += b.w;
  v.x = v.x / (1.f + __expf(-v.x));
  v.y = v.y / (1.f + __expf(-v.y));
  v.z = v.z / (1.f + __expf(-v.z));
  v.w = v.w / (1.f + __expf(-v.w));
  if (OUTBF16) {
    ushort4 o; o.x = f2bf(v.x); o.y = f2bf(v.y); o.z = f2bf(v.z); o.w = f2bf(v.w);
    ((ushort4*)outp)[i] = o;
  } else {
    ((float4*)outp)[i] = v;
  }
}

// ---------- V transpose: KV(S,2048) -> VT(G,128,S) ----------
__global__ __launch_bounds__(256) void vtrans(const ushort* __restrict__ KV,
                                              ushort* __restrict__ VT) {
  __shared__ ushort Vl[64 * 138];
  const int tid = threadIdx.x;
  const int t0 = blockIdx.x * 64;
  const int g = blockIdx.y;
#pragma unroll
  for (int i = 0; i < 16; i++) {
    int idx = tid + i * 256;
    int r = idx >> 6, dc = idx & 63;
    *(uint*)&Vl[r * 138 + dc * 2] =
        *(const uint*)&KV[(size_t)(t0 + r) * 2048 + 1024 + g * 128 + dc * 2];
  }
  __syncthreads();
#pragma unroll
  for (int i = 0; i < 4; i++) {
    int idx = tid + i * 256;
    int dv = idx >> 3, tch = idx & 7;
    short8 o;
#pragma unroll
    for (int j = 0; j < 8; j++) o[j] = (short)Vl[(tch * 8 + j) * 138 + dv];
    *(short8*)&VT[(size_t)g * 131072 + (size_t)dv * 1024 + t0 + tch * 8] = o;
  }
}

// ---------- Flash attention v7: LDS diet (no V staging) -> 2 blocks/CU ----------
// Grid 512 (1D). XCD swizzle maps one KV-group per XCD (512 = 8 XCD x 64 blocks,
// 64 blocks = 16 heads x 4 qb = exactly one group).
// LDS: Kl[2] (32K) + Pl (34K) + Ls (1K) = 67K -> 2 blocks/CU, 16 waves/CU.
// V read directly from L2-resident VT (per-group 256KB); loads issued before QK
// so ~200cy L2 latency hides under the QK MFMA+softmax phase and is drained by
// the existing second __syncthreads.
__global__ __launch_bounds__(512, 4) void attn6(const ushort* __restrict__ Q,
                                                const ushort* __restrict__ KV,
                                                const ushort* __restrict__ VT,
                                                ushort* __restrict__ Z) {
  __shared__ ushort Kl[2][64 * 128];   // [T][dq] unpadded, XOR chunk swizzle
  __shared__ ushort Pl[256 * 68];      // [row][T] ld=68
  __shared__ float  Ls[256];
  const int tid = threadIdx.x;
  const int w = tid >> 6;
  const int lane = tid & 63;
  const int c16 = lane & 15;
  const int quad = lane >> 4;
  // XCD-aware swizzle: 512 blocks over 8 XCDs, contiguous 64-block chunk per XCD
  const int b = (blockIdx.x & 7) * 64 + (blockIdx.x >> 3);
  const int hh = b >> 2;
  const int qb = b & 3;
  const int g = hh >> 4;
  const int prow0 = (w & 3) * 64;      // PV rows (block-local)
  const int dv0 = (w >> 2) * 64;       // PV dv half

  const ushort* Kg = KV + (size_t)g * 128;
  const ushort* Vg = VT + (size_t)g * 131072;

  // QK fragments: rows [qb*256 + w*32, +32)
  short8 aq[2][4];
#pragma unroll
  for (int mt = 0; mt < 2; mt++)
#pragma unroll
    for (int kc = 0; kc < 4; kc++)
      aq[mt][kc] = *(const short8*)&Q[(size_t)(qb * 256 + w * 32 + mt * 16 + c16) * 16384 +
                                      hh * 128 + kc * 32 + quad * 8];

  const floatx4 zero = {0.f, 0.f, 0.f, 0.f};
  floatx4 o[4][4];
  float lacc[2][4];
#pragma unroll
  for (int mt = 0; mt < 4; mt++)
#pragma unroll
    for (int nt = 0; nt < 4; nt++) o[mt][nt] = zero;
#pragma unroll
  for (int mt = 0; mt < 2; mt++)
#pragma unroll
    for (int r = 0; r < 4; r++) lacc[mt][r] = 0.f;

  // K staging geometry (per wave: 2 issues, 16B chunks)
  const int kr16 = lane >> 4;          // K: row-within-issue
  const int kc16 = lane & 15;          // K: chunk pos (16 chunks/row)

  auto stage = [&](int buf, int t0) {
#pragma unroll
    for (int i = 0; i < 2; i++) {
      int krow = w * 8 + i * 4 + kr16;
      int kcs = kc16 ^ (krow & 7);
      lds_dma16(&Kg[(size_t)(t0 + krow) * 2048 + kcs * 8],
                (void*)(&Kl[buf][w * 1024 + i * 512]));
    }
  };

  stage(0, 0);  // prologue: tile 0

  for (int t = 0; t < 16; t++) {
    const int p = t & 1;
    __syncthreads();                    // drains K DMA: K(t) staged; Pl free
    if (t < 15) stage(p ^ 1, (t + 1) * 64);

    // issue V loads for this tile NOW: latency hides under QK, drained at barrier #2
    short8 bv[2][4];
#pragma unroll
    for (int tc = 0; tc < 2; tc++)
#pragma unroll
      for (int nt = 0; nt < 4; nt++)
        bv[tc][nt] = *(const short8*)&Vg[(size_t)(dv0 + nt * 16 + c16) * 1024 +
                                         t * 64 + tc * 32 + quad * 8];

    // ---- QK: 32 rows x 64 T ----
#pragma unroll
    for (int st = 0; st < 4; st++) {
      floatx4 s0 = zero, s1 = zero;
      const int krow = st * 16 + c16;
      __builtin_amdgcn_s_setprio(1);
#pragma unroll
      for (int kc = 0; kc < 4; kc++) {
        short8 bk = *(const short8*)&Kl[p][krow * 128 + (((kc * 4 + quad) ^ (c16 & 7)) << 3)];
        s0 = __builtin_amdgcn_mfma_f32_16x16x32_bf16(aq[0][kc], bk, s0, 0, 0, 0);
        s1 = __builtin_amdgcn_mfma_f32_16x16x32_bf16(aq[1][kc], bk, s1, 0, 0, 0);
      }
      __builtin_amdgcn_s_setprio(0);
#pragma unroll
      for (int r = 0; r < 4; r++) {
        float p0 = __expf(s0[r]);
        float p1 = __expf(s1[r]);
        lacc[0][r] += p0;
        lacc[1][r] += p1;
        Pl[(w * 32 + quad * 4 + r) * 68 + st * 16 + c16] = f2bf(p0);
        Pl[(w * 32 + 16 + quad * 4 + r) * 68 + st * 16 + c16] = f2bf(p1);
      }
    }
    __syncthreads();                    // P visible (also drains t+1 DMA + bv loads)

    // ---- PV: 64 rows x 64 dv ----
#pragma unroll
    for (int tc = 0; tc < 2; tc++) {
      short8 ap[4];
#pragma unroll
      for (int mt = 0; mt < 4; mt++)
        ap[mt] = *(const short8*)&Pl[(prow0 + mt * 16 + c16) * 68 + tc * 32 + quad * 8];
      __builtin_amdgcn_s_setprio(1);
#pragma unroll
      for (int nt = 0; nt < 4; nt++) {
#pragma unroll
        for (int mt = 0; mt < 4; mt++)
          o[mt][nt] = __builtin_amdgcn_mfma_f32_16x16x32_bf16(ap[mt], bv[tc][nt], o[mt][nt], 0, 0, 0);
      }
      __builtin_amdgcn_s_setprio(0);
    }
  }

  // final l reduction (QK rows of this wave) -> Ls
#pragma unroll
  for (int mt = 0; mt < 2; mt++) {
#pragma unroll
    for (int r = 0; r < 4; r++) {
      float l = lacc[mt][r];
      l += __shfl_xor(l, 1);
      l += __shfl_xor(l, 2);
      l += __shfl_xor(l, 4);
      l += __shfl_xor(l, 8);
      if (c16 == 0) Ls[w * 32 + mt * 16 + quad * 4 + r] = l;
    }
  }
  __syncthreads();

  // epilogue: write O / l
#pragma unroll
  for (int mt = 0; mt < 4; mt++) {
#pragma unroll
    for (int r = 0; r < 4; r++) {
      const float inv = 1.f / Ls[prow0 + mt * 16 + quad * 4 + r];
      const size_t row = (size_t)qb * 256 + prow0 + mt * 16 + quad * 4 + r;
#pragma unroll
      for (int nt = 0; nt < 4; nt++)
        Z[row * 16384 + hh * 128 + dv0 + nt * 16 + c16] = f2bf(o[mt][nt][r] * inv);
    }
  }
}

// ---------- host ----------
extern "C" void kernel_launch(void* const* d_in, const int* in_sizes, int n_in,
                              void* d_out, int out_size, void* d_ws, size_t ws_size,
                              hipStream_t stream) {
  (void)in_sizes; (void)n_in; (void)out_size; (void)ws_size;
  const float* x        = (const float*)d_in[0];
  const float* gamma_in = (const float*)d_in[1];
  const float* Wq_w     = (const float*)d_in[2];
  const float* Wq_b     = (const float*)d_in[3];
  const float* Wkv_w    = (const float*)d_in[4];
  const float* Wkv_b    = (const float*)d_in[5];
  const float* gamma_z  = (const float*)d_in[6];
  const float* W1       = (const float*)d_in[7];
  const float* b1       = (const float*)d_in[8];
  const float* W2       = (const float*)d_in[9];
  const float* b2       = (const float*)d_in[10];
  float* out = (float*)d_out;

  char* ws = (char*)d_ws;
  size_t off = 0;
  auto alloc = [&](size_t bytes) {
    void* p = ws + off;
    off += (bytes + 255) & ~(size_t)255;
    return p;
  };
  ushort* xn   = (ushort*)alloc((size_t)1024 * 1024 * 2);    //  2 MB
  ushort* Wqb  = (ushort*)alloc((size_t)16384 * 1024 * 2);   // 32 MB (Wkvb contiguous after)
  ushort* Wkvb = (ushort*)alloc((size_t)2048 * 1024 * 2);    //  4 MB
  ushort* W1b  = (ushort*)alloc((size_t)2048 * 16384 * 2);   // 64 MB
  ushort* W2b  = (ushort*)alloc((size_t)1024 * 2048 * 2);    //  4 MB
  ushort* Qb   = (ushort*)alloc((size_t)1024 * 16384 * 2);   // 32 MB
  ushort* KVb  = (ushort*)alloc((size_t)1024 * 2048 * 2);    //  4 MB
  // time-disjoint aliases (stream-ordered):
  ushort* Zb   = Wqb;            // attention out (32 MB) — after QKV-GEMM reads Wqb
  ushort* VTb  = Wkvb;           // V^T (4 MB) — after QKV-GEMM reads Wkvb
  ushort* ZN   = Qb;             // rmsnorm(z) — after attention reads Qb
  float*  h1f  = (float*)Wqb;    // W1 partials: 4 planes x 8 MB — after rmsnorm reads Zb
  ushort* H1   = Wkvb;           // silu(h1) bf16 (4 MB) — after attention reads VTb
  float*  outf = (float*)Qb;     // W2 partials: 4 planes x 4 MB — after W1-GEMM reads ZN

  cvt_all<<<16384 + 2048 + 32768 + 2048, 256, 0, stream>>>(
      Wq_w, Wqb, 16384, Wkv_w, Wkvb, 2048, W1, W1b, 32768, W2, W2b);

  rmsnorm_f32<<<1024, 256, 0, stream>>>(x, gamma_in, xn, 1024, 32.0f);

  // fused Q+KV projection; Q pre-scaled by 1/sqrt(128)
  { dim3 g(8, 144, 1);
    gemm3<2, 0, 1><<<g, 256, 0, stream>>>(xn, Wqb, Wq_b, Wkv_b, Qb, KVb,
                                          1024, 18432, 1024, 1024, 0.08838834764831845f); }

  { dim3 g(16, 8); vtrans<<<g, 256, 0, stream>>>(KVb, VTb); }

  attn6<<<512, 512, 0, stream>>>(Qb, KVb, VTb, Zb);

  rmsnorm_bf16<<<1024, 256, 0, stream>>>(Zb, gamma_z, ZN, 16384, 128.0f);

  // W1: split-K=4 disjoint fp32 planes, then sum+bias+SiLU -> bf16
  { dim3 g(8, 16, 4);
    gemm3<1, 0, 0><<<g, 256, 0, stream>>>(ZN, W1b, b1, nullptr, h1f, nullptr,
                                          1024, 2048, 16384, 4096, 0.f); }
  epi_sum_silu<4, 1><<<2048, 256, 0, stream>>>(h1f, b1, H1, 2048, 1024 * 2048 / 4,
                                               (size_t)1024 * 2048 / 4);

  // W2: split-K=4 planes, then sum+bias+SiLU -> fp32 out
  { dim3 g(8, 8, 4);
    gemm3<1, 0, 0><<<g, 256, 0, stream>>>(H1, W2b, b2, nullptr, outf, nullptr,
                                          1024, 1024, 2048, 512, 0.f); }
  epi_sum_silu<4, 0><<<1024, 256, 0, stream>>>(outf, b2, out, 1024, 1024 * 1024 / 4,
                                               (size_t)1024 * 1024 / 4);
}

// Round 3
// 575.384 us; speedup vs baseline: 1.4691x; 1.4691x over previous
//
#include <hip/hip_runtime.h>
#include <hip/hip_bf16.h>
#include <math.h>

typedef __attribute__((ext_vector_type(8))) short short8;   // 8 x bf16 (MFMA frag)
typedef __attribute__((ext_vector_type(4))) float floatx4;  // MFMA accumulator

__device__ __forceinline__ ushort f2bf(float f) {
  __hip_bfloat16 h = __float2bfloat16(f);
  return *reinterpret_cast<ushort*>(&h);
}
__device__ __forceinline__ float bf2f(ushort u) {
  union { unsigned int i; float f; } c; c.i = ((unsigned)u) << 16; return c.f;
}

// async global->LDS 16B DMA (dest = wave-uniform base + lane*16)
__device__ __forceinline__ void lds_dma16(const void* g, void* l) {
  __builtin_amdgcn_global_load_lds((const __attribute__((address_space(1))) void*)g,
                                   (__attribute__((address_space(3))) void*)l, 16, 0, 0);
}

// ---------- fused fp32 -> bf16 conversion for all four weights ----------
__global__ __launch_bounds__(256) void cvt_all(const float* __restrict__ p0, ushort* __restrict__ o0, int b0,
                                               const float* __restrict__ p1, ushort* __restrict__ o1, int b1,
                                               const float* __restrict__ p2, ushort* __restrict__ o2, int b2,
                                               const float* __restrict__ p3, ushort* __restrict__ o3) {
  int b = blockIdx.x;
  const float* in; ushort* out; int base;
  if (b < b0)            { in = p0; out = o0; base = 0; }
  else if (b < b0 + b1)  { in = p1; out = o1; base = b0; }
  else if (b < b0 + b1 + b2) { in = p2; out = o2; base = b0 + b1; }
  else                   { in = p3; out = o3; base = b0 + b1 + b2; }
  int i = (b - base) * 256 + threadIdx.x;
  float4 v = ((const float4*)in)[i];
  ushort4 o;
  o.x = f2bf(v.x); o.y = f2bf(v.y); o.z = f2bf(v.z); o.w = f2bf(v.w);
  ((ushort4*)out)[i] = o;
}

// ---------- RMSNorm fp32 -> bf16 ----------
__global__ __launch_bounds__(256) void rmsnorm_f32(const float* __restrict__ x,
                                                   const float* __restrict__ gamma,
                                                   ushort* __restrict__ y, int D, float sqrtD) {
  const int row = blockIdx.x;
  const float* xr = x + (size_t)row * D;
  float ss = 0.f;
  for (int i = threadIdx.x * 4; i < D; i += 1024) {
    float4 v = *(const float4*)&xr[i];
    ss += v.x * v.x + v.y * v.y + v.z * v.z + v.w * v.w;
  }
#pragma unroll
  for (int off = 1; off < 64; off <<= 1) ss += __shfl_xor(ss, off);
  __shared__ float red[4];
  if ((threadIdx.x & 63) == 0) red[threadIdx.x >> 6] = ss;
  __syncthreads();
  ss = red[0] + red[1] + red[2] + red[3];
  const float sc = sqrtD / fmaxf(sqrtf(ss), 1e-12f);
  for (int i = threadIdx.x * 4; i < D; i += 1024) {
    float4 v = *(const float4*)&xr[i];
    ushort4 o;
    o.x = f2bf(v.x * sc * gamma[i]);
    o.y = f2bf(v.y * sc * gamma[i + 1]);
    o.z = f2bf(v.z * sc * gamma[i + 2]);
    o.w = f2bf(v.w * sc * gamma[i + 3]);
    *(ushort4*)&y[(size_t)row * D + i] = o;
  }
}

// ---------- RMSNorm bf16 -> bf16 ----------
__global__ __launch_bounds__(256) void rmsnorm_bf16(const ushort* __restrict__ x,
                                                    const float* __restrict__ gamma,
                                                    ushort* __restrict__ y, int D, float sqrtD) {
  const int row = blockIdx.x;
  const ushort* xr = x + (size_t)row * D;
  float ss = 0.f;
  for (int i = threadIdx.x * 8; i < D; i += 2048) {
    short8 v = *(const short8*)&xr[i];
#pragma unroll
    for (int e = 0; e < 8; e++) { float f = bf2f((ushort)v[e]); ss += f * f; }
  }
#pragma unroll
  for (int off = 1; off < 64; off <<= 1) ss += __shfl_xor(ss, off);
  __shared__ float red[4];
  if ((threadIdx.x & 63) == 0) red[threadIdx.x >> 6] = ss;
  __syncthreads();
  ss = red[0] + red[1] + red[2] + red[3];
  const float sc = sqrtD / fmaxf(sqrtf(ss), 1e-12f);
  for (int i = threadIdx.x * 8; i < D; i += 2048) {
    short8 v = *(const short8*)&xr[i];
    short8 ov;
#pragma unroll
    for (int e = 0; e < 8; e++) ov[e] = (short)f2bf(bf2f((ushort)v[e]) * sc * gamma[i + e]);
    *(short8*)&y[(size_t)row * D + i] = ov;
  }
}

// ---------- GEMM v3: 128x128 tile, BK=64, global_load_lds + XOR swizzle ----------
template <int EPI, int ACT, int OUTBF16>
__global__ __launch_bounds__(256, 3) void gemm3(const ushort* __restrict__ A,
                                                const ushort* __restrict__ B,
                                                const float* __restrict__ bias,
                                                const float* __restrict__ bias2,
                                                void* __restrict__ C1,
                                                void* __restrict__ C2,
                                                int M, int N, int K, int Ksplit, float scale) {
  __shared__ ushort As[128 * 64];
  __shared__ ushort Bs[128 * 64];
  const int tid = threadIdx.x;
  const int wave = tid >> 6;
  const int lane = tid & 63;
  const int c16 = lane & 15;
  const int quad = lane >> 4;
  const int wm = wave >> 1;
  const int wn = wave & 1;
  const size_t m0 = (size_t)blockIdx.x * 128;
  const size_t n0 = (size_t)blockIdx.y * 128;
  const int kbeg = blockIdx.z * Ksplit;
  const int kend = kbeg + Ksplit;

  const int rsub = lane >> 3;
  const int csw = (lane & 7) ^ rsub;

  const floatx4 zero = {0.f, 0.f, 0.f, 0.f};
  floatx4 acc[4][4];
#pragma unroll
  for (int a = 0; a < 4; a++)
#pragma unroll
    for (int b = 0; b < 4; b++) acc[a][b] = zero;

  for (int k0 = kbeg; k0 < kend; k0 += 64) {
    __syncthreads();
#pragma unroll
    for (int i = 0; i < 4; i++) {
      const int j = wave * 4 + i;
      const int r = j * 8 + rsub;
      lds_dma16(&A[(m0 + r) * K + k0 + csw * 8], (void*)(As + j * 512));
      lds_dma16(&B[(n0 + r) * K + k0 + csw * 8], (void*)(Bs + j * 512));
    }
    __syncthreads();
#pragma unroll
    for (int kc = 0; kc < 2; kc++) {
      short8 af[4], bf4[4];
#pragma unroll
      for (int mt = 0; mt < 4; mt++) {
        const int row = wm * 64 + mt * 16 + c16;
        af[mt] = *(const short8*)&As[row * 64 + (((kc * 4 + quad) ^ (row & 7)) << 3)];
      }
#pragma unroll
      for (int nt = 0; nt < 4; nt++) {
        const int row = wn * 64 + nt * 16 + c16;
        bf4[nt] = *(const short8*)&Bs[row * 64 + (((kc * 4 + quad) ^ (row & 7)) << 3)];
      }
#pragma unroll
      for (int mt = 0; mt < 4; mt++)
#pragma unroll
        for (int nt = 0; nt < 4; nt++)
          acc[mt][nt] = __builtin_amdgcn_mfma_f32_16x16x32_bf16(af[mt], bf4[nt], acc[mt][nt], 0, 0, 0);
    }
  }

#pragma unroll
  for (int mt = 0; mt < 4; mt++) {
#pragma unroll
    for (int nt = 0; nt < 4; nt++) {
      const size_t col = n0 + wn * 64 + nt * 16 + c16;
      const size_t row0 = m0 + wm * 64 + mt * 16 + quad * 4;
      if (EPI == 0) {
        const float bv = bias[col];
#pragma unroll
        for (int r = 0; r < 4; r++) {
          float v = acc[mt][nt][r] + bv;
          if (ACT) v = v / (1.f + __expf(-v));
          if (OUTBF16) ((ushort*)C1)[(row0 + r) * N + col] = f2bf(v);
          else         ((float*)C1)[(row0 + r) * N + col] = v;
        }
      } else if (EPI == 1) {
        float* plane = (float*)C1 + (size_t)blockIdx.z * M * N;
#pragma unroll
        for (int r = 0; r < 4; r++)
          plane[(row0 + r) * N + col] = acc[mt][nt][r];
      } else {
        if (col < 16384) {
          const float bv = bias[col];
#pragma unroll
          for (int r = 0; r < 4; r++)
            ((ushort*)C1)[(row0 + r) * 16384 + col] = f2bf((acc[mt][nt][r] + bv) * scale);
        } else {
          const size_t ckv = col - 16384;
          const float bv = bias2[ckv];
#pragma unroll
          for (int r = 0; r < 4; r++)
            ((ushort*)C2)[(row0 + r) * 2048 + ckv] = f2bf(acc[mt][nt][r] + bv);
        }
      }
    }
  }
}

// ---------- split-K reduce + bias + SiLU epilogue ----------
template <int NZ, int OUTBF16>
__global__ __launch_bounds__(256) void epi_sum_silu(const float* __restrict__ accb,
                                                    const float* __restrict__ bias,
                                                    void* __restrict__ outp, int N, int n4,
                                                    size_t plane4) {
  int i = blockIdx.x * 256 + threadIdx.x;
  if (i >= n4) return;
  float4 v = ((const float4*)accb)[i];
#pragma unroll
  for (int z = 1; z < NZ; z++) {
    float4 p = ((const float4*)accb)[i + z * plane4];
    v.x += p.x; v.y += p.y; v.z += p.z; v.w += p.w;
  }
  const float4 b = *(const float4*)&bias[(i * 4) % N];
  v.x += b.x; v.y += b.y; v.z += b.z; v.w += b.w;
  v.x = v.x / (1.f + __expf(-v.x));
  v.y = v.y / (1.f + __expf(-v.y));
  v.z = v.z / (1.f + __expf(-v.z));
  v.w = v.w / (1.f + __expf(-v.w));
  if (OUTBF16) {
    ushort4 o; o.x = f2bf(v.x); o.y = f2bf(v.y); o.z = f2bf(v.z); o.w = f2bf(v.w);
    ((ushort4*)outp)[i] = o;
  } else {
    ((float4*)outp)[i] = v;
  }
}

// ---------- V transpose: KV(S,2048) -> VT(G,128,S) ----------
__global__ __launch_bounds__(256) void vtrans(const ushort* __restrict__ KV,
                                              ushort* __restrict__ VT) {
  __shared__ ushort Vl[64 * 138];
  const int tid = threadIdx.x;
  const int t0 = blockIdx.x * 64;
  const int g = blockIdx.y;
#pragma unroll
  for (int i = 0; i < 16; i++) {
    int idx = tid + i * 256;
    int r = idx >> 6, dc = idx & 63;
    *(uint*)&Vl[r * 138 + dc * 2] =
        *(const uint*)&KV[(size_t)(t0 + r) * 2048 + 1024 + g * 128 + dc * 2];
  }
  __syncthreads();
#pragma unroll
  for (int i = 0; i < 4; i++) {
    int idx = tid + i * 256;
    int dv = idx >> 3, tch = idx & 7;
    short8 o;
#pragma unroll
    for (int j = 0; j < 8; j++) o[j] = (short)Vl[(tch * 8 + j) * 138 + dv];
    *(short8*)&VT[(size_t)g * 131072 + (size_t)dv * 1024 + t0 + tch * 8] = o;
  }
}

// ---------- Flash attention v8: 80KB LDS (K dbuf + V single-buf + swizzled P) ----------
// Grid 512 (1D), XCD swizzle: one KV-group per XCD.
// LDS: Kl[2] 32K + Vt 16K + Pl(ld=64, XOR chunk swizzle) 32K = 81920 B = 80 KiB
// -> exactly 2 blocks/CU (163840 B = 160 KiB), 16 waves/CU.
// Ls aliased over Pl (Pl dead after last PV; Pl is never a DMA target).
// V single-buffered: staged after barrier1 (PV(t-1) done -> Vt free), drained
// by barrier2 before PV(t); latency hides under QK. Registers: v6 shape (~104).
__global__ __launch_bounds__(512, 2) void attn6(const ushort* __restrict__ Q,
                                                const ushort* __restrict__ KV,
                                                const ushort* __restrict__ VT,
                                                ushort* __restrict__ Z) {
  __shared__ ushort Kl[2][64 * 128];   // [T][dq] unpadded, XOR chunk swizzle
  __shared__ ushort Vt[128 * 64];      // [dv][T] unpadded, XOR chunk swizzle (single buf)
  __shared__ ushort Pl[256 * 64];      // [row][T] ld=64, XOR chunk swizzle
  float* Ls = (float*)Pl;              // [256] aliased; valid after last PV
  const int tid = threadIdx.x;
  const int w = tid >> 6;
  const int lane = tid & 63;
  const int c16 = lane & 15;
  const int quad = lane >> 4;
  // XCD-aware swizzle: 512 blocks over 8 XCDs, contiguous 64-block chunk per XCD
  const int b = (blockIdx.x & 7) * 64 + (blockIdx.x >> 3);
  const int hh = b >> 2;
  const int qb = b & 3;
  const int g = hh >> 4;
  const int prow0 = (w & 3) * 64;      // PV rows (block-local)
  const int dv0 = (w >> 2) * 64;       // PV dv half

  const ushort* Kg = KV + (size_t)g * 128;
  const ushort* Vg = VT + (size_t)g * 131072;

  // QK fragments: rows [qb*256 + w*32, +32)
  short8 aq[2][4];
#pragma unroll
  for (int mt = 0; mt < 2; mt++)
#pragma unroll
    for (int kc = 0; kc < 4; kc++)
      aq[mt][kc] = *(const short8*)&Q[(size_t)(qb * 256 + w * 32 + mt * 16 + c16) * 16384 +
                                      hh * 128 + kc * 32 + quad * 8];

  const floatx4 zero = {0.f, 0.f, 0.f, 0.f};
  floatx4 o[4][4];
  float lacc[2][4];
#pragma unroll
  for (int mt = 0; mt < 4; mt++)
#pragma unroll
    for (int nt = 0; nt < 4; nt++) o[mt][nt] = zero;
#pragma unroll
  for (int mt = 0; mt < 2; mt++)
#pragma unroll
    for (int r = 0; r < 4; r++) lacc[mt][r] = 0.f;

  // staging geometry (per wave: 2 K-issues + 2 V-issues, 16B chunks)
  const int kr16 = lane >> 4;          // K: row-within-issue
  const int kc16 = lane & 15;          // K: chunk pos (16 chunks/row)
  const int vr8 = lane >> 3;           // V: row-within-issue
  const int vc8 = lane & 7;            // V: chunk pos (8 chunks/row)

  auto stageK = [&](int buf, int t0) {
#pragma unroll
    for (int i = 0; i < 2; i++) {
      int krow = w * 8 + i * 4 + kr16;
      int kcs = kc16 ^ (krow & 7);
      lds_dma16(&Kg[(size_t)(t0 + krow) * 2048 + kcs * 8],
                (void*)(&Kl[buf][w * 1024 + i * 512]));
    }
  };
  auto stageV = [&](int t0) {
#pragma unroll
    for (int i = 0; i < 2; i++) {
      int vrow = w * 16 + i * 8 + vr8;
      int vcs = vc8 ^ (vrow & 7);
      lds_dma16(&Vg[(size_t)vrow * 1024 + t0 + vcs * 8],
                (void*)(&Vt[w * 1024 + i * 512]));
    }
  };

  stageK(0, 0);  // prologue: K tile 0

  for (int t = 0; t < 16; t++) {
    const int p = t & 1;
    __syncthreads();                    // K(t) staged; PV(t-1) done -> Vt, Pl free
    if (t < 15) stageK(p ^ 1, (t + 1) * 64);
    stageV(t * 64);                     // V(t) -> single buffer; drained at barrier2

    // ---- QK: 32 rows x 64 T ----
#pragma unroll
    for (int st = 0; st < 4; st++) {
      floatx4 s0 = zero, s1 = zero;
      const int krow = st * 16 + c16;
      __builtin_amdgcn_s_setprio(1);
#pragma unroll
      for (int kc = 0; kc < 4; kc++) {
        short8 bk = *(const short8*)&Kl[p][krow * 128 + (((kc * 4 + quad) ^ (c16 & 7)) << 3)];
        s0 = __builtin_amdgcn_mfma_f32_16x16x32_bf16(aq[0][kc], bk, s0, 0, 0, 0);
        s1 = __builtin_amdgcn_mfma_f32_16x16x32_bf16(aq[1][kc], bk, s1, 0, 0, 0);
      }
      __builtin_amdgcn_s_setprio(0);
#pragma unroll
      for (int r = 0; r < 4; r++) {
        float p0 = __expf(s0[r]);
        float p1 = __expf(s1[r]);
        lacc[0][r] += p0;
        lacc[1][r] += p1;
        // swizzled P store: element (row, col) -> row*64 + ((col>>3 ^ row&7)<<3) + (col&7)
        const int rlo = w * 32 + quad * 4 + r;          // (rlo+16)&7 == rlo&7
        const int sw = ((((st * 2) + (c16 >> 3)) ^ (rlo & 7)) << 3) | (c16 & 7);
        Pl[rlo * 64 + sw] = f2bf(p0);
        Pl[(rlo + 16) * 64 + sw] = f2bf(p1);
      }
    }
    __syncthreads();                    // P visible; V(t) + K(t+1) DMA drained

    // ---- PV: 64 rows x 64 dv ----
#pragma unroll
    for (int tc = 0; tc < 2; tc++) {
      short8 ap[4];
#pragma unroll
      for (int mt = 0; mt < 4; mt++) {
        const int row = prow0 + mt * 16 + c16;          // row&7 == c16&7
        ap[mt] = *(const short8*)&Pl[row * 64 + (((tc * 4 + quad) ^ (c16 & 7)) << 3)];
      }
      __builtin_amdgcn_s_setprio(1);
#pragma unroll
      for (int nt = 0; nt < 4; nt++) {
        const int dv = dv0 + nt * 16 + c16;             // dv&7 == c16&7
        short8 bv = *(const short8*)&Vt[dv * 64 + (((tc * 4 + quad) ^ (c16 & 7)) << 3)];
#pragma unroll
        for (int mt = 0; mt < 4; mt++)
          o[mt][nt] = __builtin_amdgcn_mfma_f32_16x16x32_bf16(ap[mt], bv, o[mt][nt], 0, 0, 0);
      }
      __builtin_amdgcn_s_setprio(0);
    }
  }

  // final l reduction (QK rows of this wave) -> Ls (aliased over Pl, now dead)
  __syncthreads();                      // all waves past last PV reads of Pl
#pragma unroll
  for (int mt = 0; mt < 2; mt++) {
#pragma unroll
    for (int r = 0; r < 4; r++) {
      float l = lacc[mt][r];
      l += __shfl_xor(l, 1);
      l += __shfl_xor(l, 2);
      l += __shfl_xor(l, 4);
      l += __shfl_xor(l, 8);
      if (c16 == 0) Ls[w * 32 + mt * 16 + quad * 4 + r] = l;
    }
  }
  __syncthreads();

  // epilogue: write O / l
#pragma unroll
  for (int mt = 0; mt < 4; mt++) {
#pragma unroll
    for (int r = 0; r < 4; r++) {
      const float inv = 1.f / Ls[prow0 + mt * 16 + quad * 4 + r];
      const size_t row = (size_t)qb * 256 + prow0 + mt * 16 + quad * 4 + r;
#pragma unroll
      for (int nt = 0; nt < 4; nt++)
        Z[row * 16384 + hh * 128 + dv0 + nt * 16 + c16] = f2bf(o[mt][nt][r] * inv);
    }
  }
}

// ---------- host ----------
extern "C" void kernel_launch(void* const* d_in, const int* in_sizes, int n_in,
                              void* d_out, int out_size, void* d_ws, size_t ws_size,
                              hipStream_t stream) {
  (void)in_sizes; (void)n_in; (void)out_size; (void)ws_size;
  const float* x        = (const float*)d_in[0];
  const float* gamma_in = (const float*)d_in[1];
  const float* Wq_w     = (const float*)d_in[2];
  const float* Wq_b     = (const float*)d_in[3];
  const float* Wkv_w    = (const float*)d_in[4];
  const float* Wkv_b    = (const float*)d_in[5];
  const float* gamma_z  = (const float*)d_in[6];
  const float* W1       = (const float*)d_in[7];
  const float* b1       = (const float*)d_in[8];
  const float* W2       = (const float*)d_in[9];
  const float* b2       = (const float*)d_in[10];
  float* out = (float*)d_out;

  char* ws = (char*)d_ws;
  size_t off = 0;
  auto alloc = [&](size_t bytes) {
    void* p = ws + off;
    off += (bytes + 255) & ~(size_t)255;
    return p;
  };
  ushort* xn   = (ushort*)alloc((size_t)1024 * 1024 * 2);    //  2 MB
  ushort* Wqb  = (ushort*)alloc((size_t)16384 * 1024 * 2);   // 32 MB (Wkvb contiguous after)
  ushort* Wkvb = (ushort*)alloc((size_t)2048 * 1024 * 2);    //  4 MB
  ushort* W1b  = (ushort*)alloc((size_t)2048 * 16384 * 2);   // 64 MB
  ushort* W2b  = (ushort*)alloc((size_t)1024 * 2048 * 2);    //  4 MB
  ushort* Qb   = (ushort*)alloc((size_t)1024 * 16384 * 2);   // 32 MB
  ushort* KVb  = (ushort*)alloc((size_t)1024 * 2048 * 2);    //  4 MB
  // time-disjoint aliases (stream-ordered):
  ushort* Zb   = Wqb;            // attention out (32 MB) — after QKV-GEMM reads Wqb
  ushort* VTb  = Wkvb;           // V^T (4 MB) — after QKV-GEMM reads Wkvb
  ushort* ZN   = Qb;             // rmsnorm(z) — after attention reads Qb
  float*  h1f  = (float*)Wqb;    // W1 partials: 4 planes x 8 MB — after rmsnorm reads Zb
  ushort* H1   = Wkvb;           // silu(h1) bf16 (4 MB) — after attention reads VTb
  float*  outf = (float*)Qb;     // W2 partials: 4 planes x 4 MB — after W1-GEMM reads ZN

  cvt_all<<<16384 + 2048 + 32768 + 2048, 256, 0, stream>>>(
      Wq_w, Wqb, 16384, Wkv_w, Wkvb, 2048, W1, W1b, 32768, W2, W2b);

  rmsnorm_f32<<<1024, 256, 0, stream>>>(x, gamma_in, xn, 1024, 32.0f);

  // fused Q+KV projection; Q pre-scaled by 1/sqrt(128)
  { dim3 g(8, 144, 1);
    gemm3<2, 0, 1><<<g, 256, 0, stream>>>(xn, Wqb, Wq_b, Wkv_b, Qb, KVb,
                                          1024, 18432, 1024, 1024, 0.08838834764831845f); }

  { dim3 g(16, 8); vtrans<<<g, 256, 0, stream>>>(KVb, VTb); }

  attn6<<<512, 512, 0, stream>>>(Qb, KVb, VTb, Zb);

  rmsnorm_bf16<<<1024, 256, 0, stream>>>(Zb, gamma_z, ZN, 16384, 128.0f);

  // W1: split-K=4 disjoint fp32 planes, then sum+bias+SiLU -> bf16
  { dim3 g(8, 16, 4);
    gemm3<1, 0, 0><<<g, 256, 0, stream>>>(ZN, W1b, b1, nullptr, h1f, nullptr,
                                          1024, 2048, 16384, 4096, 0.f); }
  epi_sum_silu<4, 1><<<2048, 256, 0, stream>>>(h1f, b1, H1, 2048, 1024 * 2048 / 4,
                                               (size_t)1024 * 2048 / 4);

  // W2: split-K=4 planes, then sum+bias+SiLU -> fp32 out
  { dim3 g(8, 8, 4);
    gemm3<1, 0, 0><<<g, 256, 0, stream>>>(H1, W2b, b2, nullptr, outf, nullptr,
                                          1024, 1024, 2048, 512, 0.f); }
  epi_sum_silu<4, 0><<<1024, 256, 0, stream>>>(outf, b2, out, 1024, 1024 * 1024 / 4,
                                               (size_t)1024 * 1024 / 4);
}

// Round 4
// 568.326 us; speedup vs baseline: 1.4874x; 1.0124x over previous
//
#include <hip/hip_runtime.h>
#include <hip/hip_bf16.h>
#include <math.h>

typedef __attribute__((ext_vector_type(8))) short short8;   // 8 x bf16 (MFMA frag)
typedef __attribute__((ext_vector_type(4))) float floatx4;  // MFMA accumulator

__device__ __forceinline__ ushort f2bf(float f) {
  __hip_bfloat16 h = __float2bfloat16(f);
  return *reinterpret_cast<ushort*>(&h);
}
__device__ __forceinline__ float bf2f(ushort u) {
  union { unsigned int i; float f; } c; c.i = ((unsigned)u) << 16; return c.f;
}

// async global->LDS 16B DMA (dest = wave-uniform base + lane*16)
__device__ __forceinline__ void lds_dma16(const void* g, void* l) {
  __builtin_amdgcn_global_load_lds((const __attribute__((address_space(1))) void*)g,
                                   (__attribute__((address_space(3))) void*)l, 16, 0, 0);
}

// ---------- fused fp32 -> bf16 conversion for all four weights ----------
__global__ __launch_bounds__(256) void cvt_all(const float* __restrict__ p0, ushort* __restrict__ o0, int b0,
                                               const float* __restrict__ p1, ushort* __restrict__ o1, int b1,
                                               const float* __restrict__ p2, ushort* __restrict__ o2, int b2,
                                               const float* __restrict__ p3, ushort* __restrict__ o3) {
  int b = blockIdx.x;
  const float* in; ushort* out; int base;
  if (b < b0)            { in = p0; out = o0; base = 0; }
  else if (b < b0 + b1)  { in = p1; out = o1; base = b0; }
  else if (b < b0 + b1 + b2) { in = p2; out = o2; base = b0 + b1; }
  else                   { in = p3; out = o3; base = b0 + b1 + b2; }
  int i = (b - base) * 256 + threadIdx.x;
  float4 v = ((const float4*)in)[i];
  ushort4 o;
  o.x = f2bf(v.x); o.y = f2bf(v.y); o.z = f2bf(v.z); o.w = f2bf(v.w);
  ((ushort4*)out)[i] = o;
}

// ---------- RMSNorm fp32 -> bf16 ----------
__global__ __launch_bounds__(256) void rmsnorm_f32(const float* __restrict__ x,
                                                   const float* __restrict__ gamma,
                                                   ushort* __restrict__ y, int D, float sqrtD) {
  const int row = blockIdx.x;
  const float* xr = x + (size_t)row * D;
  float ss = 0.f;
  for (int i = threadIdx.x * 4; i < D; i += 1024) {
    float4 v = *(const float4*)&xr[i];
    ss += v.x * v.x + v.y * v.y + v.z * v.z + v.w * v.w;
  }
#pragma unroll
  for (int off = 1; off < 64; off <<= 1) ss += __shfl_xor(ss, off);
  __shared__ float red[4];
  if ((threadIdx.x & 63) == 0) red[threadIdx.x >> 6] = ss;
  __syncthreads();
  ss = red[0] + red[1] + red[2] + red[3];
  const float sc = sqrtD / fmaxf(sqrtf(ss), 1e-12f);
  for (int i = threadIdx.x * 4; i < D; i += 1024) {
    float4 v = *(const float4*)&xr[i];
    ushort4 o;
    o.x = f2bf(v.x * sc * gamma[i]);
    o.y = f2bf(v.y * sc * gamma[i + 1]);
    o.z = f2bf(v.z * sc * gamma[i + 2]);
    o.w = f2bf(v.w * sc * gamma[i + 3]);
    *(ushort4*)&y[(size_t)row * D + i] = o;
  }
}

// ---------- RMSNorm bf16 -> bf16 ----------
__global__ __launch_bounds__(256) void rmsnorm_bf16(const ushort* __restrict__ x,
                                                    const float* __restrict__ gamma,
                                                    ushort* __restrict__ y, int D, float sqrtD) {
  const int row = blockIdx.x;
  const ushort* xr = x + (size_t)row * D;
  float ss = 0.f;
  for (int i = threadIdx.x * 8; i < D; i += 2048) {
    short8 v = *(const short8*)&xr[i];
#pragma unroll
    for (int e = 0; e < 8; e++) { float f = bf2f((ushort)v[e]); ss += f * f; }
  }
#pragma unroll
  for (int off = 1; off < 64; off <<= 1) ss += __shfl_xor(ss, off);
  __shared__ float red[4];
  if ((threadIdx.x & 63) == 0) red[threadIdx.x >> 6] = ss;
  __syncthreads();
  ss = red[0] + red[1] + red[2] + red[3];
  const float sc = sqrtD / fmaxf(sqrtf(ss), 1e-12f);
  for (int i = threadIdx.x * 8; i < D; i += 2048) {
    short8 v = *(const short8*)&xr[i];
    short8 ov;
#pragma unroll
    for (int e = 0; e < 8; e++) ov[e] = (short)f2bf(bf2f((ushort)v[e]) * sc * gamma[i + e]);
    *(short8*)&y[(size_t)row * D + i] = ov;
  }
}

// ---------- GEMM v3: 128x128 tile, BK=64, global_load_lds + XOR swizzle ----------
template <int EPI, int ACT, int OUTBF16>
__global__ __launch_bounds__(256, 3) void gemm3(const ushort* __restrict__ A,
                                                const ushort* __restrict__ B,
                                                const float* __restrict__ bias,
                                                const float* __restrict__ bias2,
                                                void* __restrict__ C1,
                                                void* __restrict__ C2,
                                                int M, int N, int K, int Ksplit, float scale) {
  __shared__ ushort As[128 * 64];
  __shared__ ushort Bs[128 * 64];
  const int tid = threadIdx.x;
  const int wave = tid >> 6;
  const int lane = tid & 63;
  const int c16 = lane & 15;
  const int quad = lane >> 4;
  const int wm = wave >> 1;
  const int wn = wave & 1;
  const size_t m0 = (size_t)blockIdx.x * 128;
  const size_t n0 = (size_t)blockIdx.y * 128;
  const int kbeg = blockIdx.z * Ksplit;
  const int kend = kbeg + Ksplit;

  const int rsub = lane >> 3;
  const int csw = (lane & 7) ^ rsub;

  const floatx4 zero = {0.f, 0.f, 0.f, 0.f};
  floatx4 acc[4][4];
#pragma unroll
  for (int a = 0; a < 4; a++)
#pragma unroll
    for (int b = 0; b < 4; b++) acc[a][b] = zero;

  for (int k0 = kbeg; k0 < kend; k0 += 64) {
    __syncthreads();
#pragma unroll
    for (int i = 0; i < 4; i++) {
      const int j = wave * 4 + i;
      const int r = j * 8 + rsub;
      lds_dma16(&A[(m0 + r) * K + k0 + csw * 8], (void*)(As + j * 512));
      lds_dma16(&B[(n0 + r) * K + k0 + csw * 8], (void*)(Bs + j * 512));
    }
    __syncthreads();
#pragma unroll
    for (int kc = 0; kc < 2; kc++) {
      short8 af[4], bf4[4];
#pragma unroll
      for (int mt = 0; mt < 4; mt++) {
        const int row = wm * 64 + mt * 16 + c16;
        af[mt] = *(const short8*)&As[row * 64 + (((kc * 4 + quad) ^ (row & 7)) << 3)];
      }
#pragma unroll
      for (int nt = 0; nt < 4; nt++) {
        const int row = wn * 64 + nt * 16 + c16;
        bf4[nt] = *(const short8*)&Bs[row * 64 + (((kc * 4 + quad) ^ (row & 7)) << 3)];
      }
#pragma unroll
      for (int mt = 0; mt < 4; mt++)
#pragma unroll
        for (int nt = 0; nt < 4; nt++)
          acc[mt][nt] = __builtin_amdgcn_mfma_f32_16x16x32_bf16(af[mt], bf4[nt], acc[mt][nt], 0, 0, 0);
    }
  }

#pragma unroll
  for (int mt = 0; mt < 4; mt++) {
#pragma unroll
    for (int nt = 0; nt < 4; nt++) {
      const size_t col = n0 + wn * 64 + nt * 16 + c16;
      const size_t row0 = m0 + wm * 64 + mt * 16 + quad * 4;
      if (EPI == 0) {
        const float bv = bias[col];
#pragma unroll
        for (int r = 0; r < 4; r++) {
          float v = acc[mt][nt][r] + bv;
          if (ACT) v = v / (1.f + __expf(-v));
          if (OUTBF16) ((ushort*)C1)[(row0 + r) * N + col] = f2bf(v);
          else         ((float*)C1)[(row0 + r) * N + col] = v;
        }
      } else if (EPI == 1) {
        float* plane = (float*)C1 + (size_t)blockIdx.z * M * N;
#pragma unroll
        for (int r = 0; r < 4; r++)
          plane[(row0 + r) * N + col] = acc[mt][nt][r];
      } else {
        if (col < 16384) {
          const float bv = bias[col];
#pragma unroll
          for (int r = 0; r < 4; r++)
            ((ushort*)C1)[(row0 + r) * 16384 + col] = f2bf((acc[mt][nt][r] + bv) * scale);
        } else {
          const size_t ckv = col - 16384;
          const float bv = bias2[ckv];
#pragma unroll
          for (int r = 0; r < 4; r++)
            ((ushort*)C2)[(row0 + r) * 2048 + ckv] = f2bf(acc[mt][nt][r] + bv);
        }
      }
    }
  }
}

// ---------- split-K reduce + bias + SiLU epilogue ----------
template <int NZ, int OUTBF16>
__global__ __launch_bounds__(256) void epi_sum_silu(const float* __restrict__ accb,
                                                    const float* __restrict__ bias,
                                                    void* __restrict__ outp, int N, int n4,
                                                    size_t plane4) {
  int i = blockIdx.x * 256 + threadIdx.x;
  if (i >= n4) return;
  float4 v = ((const float4*)accb)[i];
#pragma unroll
  for (int z = 1; z < NZ; z++) {
    float4 p = ((const float4*)accb)[i + z * plane4];
    v.x += p.x; v.y += p.y; v.z += p.z; v.w += p.w;
  }
  const float4 b = *(const float4*)&bias[(i * 4) % N];
  v.x += b.x; v.y += b.y; v.z += b.z; v.w += b.w;
  v.x = v.x / (1.f + __expf(-v.x));
  v.y = v.y / (1.f + __expf(-v.y));
  v.z = v.z / (1.f + __expf(-v.z));
  v.w = v.w / (1.f + __expf(-v.w));
  if (OUTBF16) {
    ushort4 o; o.x = f2bf(v.x); o.y = f2bf(v.y); o.z = f2bf(v.z); o.w = f2bf(v.w);
    ((ushort4*)outp)[i] = o;
  } else {
    ((float4*)outp)[i] = v;
  }
}

// ---------- V transpose: KV(S,2048) -> VT(G,128,S) ----------
__global__ __launch_bounds__(256) void vtrans(const ushort* __restrict__ KV,
                                              ushort* __restrict__ VT) {
  __shared__ ushort Vl[64 * 138];
  const int tid = threadIdx.x;
  const int t0 = blockIdx.x * 64;
  const int g = blockIdx.y;
#pragma unroll
  for (int i = 0; i < 16; i++) {
    int idx = tid + i * 256;
    int r = idx >> 6, dc = idx & 63;
    *(uint*)&Vl[r * 138 + dc * 2] =
        *(const uint*)&KV[(size_t)(t0 + r) * 2048 + 1024 + g * 128 + dc * 2];
  }
  __syncthreads();
#pragma unroll
  for (int i = 0; i < 4; i++) {
    int idx = tid + i * 256;
    int dv = idx >> 3, tch = idx & 7;
    short8 o;
#pragma unroll
    for (int j = 0; j < 8; j++) o[j] = (short)Vl[(tch * 8 + j) * 138 + dv];
    *(short8*)&VT[(size_t)g * 131072 + (size_t)dv * 1024 + t0 + tch * 8] = o;
  }
}

// ---------- Flash attention v9: slim waves for 2 blocks/CU ----------
// Grid 1024 x 512 threads. Block covers 128 Q rows of head hh: hh = b>>3, qb = b&7.
// Per wave: QK 16 rows (aq[4]=16 regs, single s0 chain), PV 32 rows x 64 dv
// (o[2][4]=32 acc regs). Persistent live ~52 regs, peak ~110 -> fits the 128-reg
// cap from __launch_bounds__(512,4) without v7's spill. LDS: Kl[2] 32K + Vt 16K
// + Pl[128][64] 16K = 64 KiB -> 2 blocks/CU (128 KiB), 16 waves/CU, 4 waves/SIMD.
// Two independent blocks interleave QK(VALU)/PV(MFMA)/staging phases per CU.
// XCD swizzle: 1024 blocks = 8 XCD x 128; one KV-group per XCD.
__global__ __launch_bounds__(512, 4) void attn9(const ushort* __restrict__ Q,
                                                const ushort* __restrict__ KV,
                                                const ushort* __restrict__ VT,
                                                ushort* __restrict__ Z) {
  __shared__ ushort Kl[2][64 * 128];   // [T][dq] unpadded, XOR chunk swizzle
  __shared__ ushort Vt[128 * 64];      // [dv][T] unpadded, XOR chunk swizzle (single buf)
  __shared__ ushort Pl[128 * 64];      // [row][T] ld=64, XOR chunk swizzle
  float* Ls = (float*)Pl;              // [128] aliased; valid after last PV
  const int tid = threadIdx.x;
  const int w = tid >> 6;              // 0..7
  const int lane = tid & 63;
  const int c16 = lane & 15;
  const int quad = lane >> 4;
  // XCD-aware swizzle: 1024 blocks over 8 XCDs, contiguous 128-block chunk per XCD
  const int b = (blockIdx.x & 7) * 128 + (blockIdx.x >> 3);
  const int hh = b >> 3;               // head 0..127
  const int qb = b & 7;                // 128-row chunk of S=1024
  const int g = hh >> 4;
  const int prow0 = (w & 3) * 32;      // PV rows (block-local)
  const int dv0 = (w >> 2) * 64;       // PV dv half

  const ushort* Kg = KV + (size_t)g * 128;
  const ushort* Vg = VT + (size_t)g * 131072;

  // QK fragments: rows [qb*128 + w*16, +16)
  short8 aq[4];
#pragma unroll
  for (int kc = 0; kc < 4; kc++)
    aq[kc] = *(const short8*)&Q[(size_t)(qb * 128 + w * 16 + c16) * 16384 +
                                hh * 128 + kc * 32 + quad * 8];

  const floatx4 zero = {0.f, 0.f, 0.f, 0.f};
  floatx4 o[2][4];
  float lacc[4];
#pragma unroll
  for (int mt = 0; mt < 2; mt++)
#pragma unroll
    for (int nt = 0; nt < 4; nt++) o[mt][nt] = zero;
#pragma unroll
  for (int r = 0; r < 4; r++) lacc[r] = 0.f;

  // staging geometry (per wave: 2 K-issues + 2 V-issues, 16B chunks)
  const int kr16 = lane >> 4;          // K: row-within-issue
  const int kc16 = lane & 15;          // K: chunk pos (16 chunks/row)
  const int vr8 = lane >> 3;           // V: row-within-issue
  const int vc8 = lane & 7;            // V: chunk pos (8 chunks/row)

  auto stageK = [&](int buf, int t0) {
#pragma unroll
    for (int i = 0; i < 2; i++) {
      int krow = w * 8 + i * 4 + kr16;
      int kcs = kc16 ^ (krow & 7);
      lds_dma16(&Kg[(size_t)(t0 + krow) * 2048 + kcs * 8],
                (void*)(&Kl[buf][w * 1024 + i * 512]));
    }
  };
  auto stageV = [&](int t0) {
#pragma unroll
    for (int i = 0; i < 2; i++) {
      int vrow = w * 16 + i * 8 + vr8;
      int vcs = vc8 ^ (vrow & 7);
      lds_dma16(&Vg[(size_t)vrow * 1024 + t0 + vcs * 8],
                (void*)(&Vt[w * 1024 + i * 512]));
    }
  };

  stageK(0, 0);  // prologue: K tile 0

  for (int t = 0; t < 16; t++) {
    const int p = t & 1;
    __syncthreads();                    // K(t) staged; PV(t-1) done -> Vt, Pl free
    if (t < 15) stageK(p ^ 1, (t + 1) * 64);
    stageV(t * 64);                     // V(t) -> single buffer; drained at barrier2

    // ---- QK: 16 rows x 64 T per wave ----
#pragma unroll
    for (int st = 0; st < 4; st++) {
      floatx4 s0 = zero;
      const int krow = st * 16 + c16;
      __builtin_amdgcn_s_setprio(1);
#pragma unroll
      for (int kc = 0; kc < 4; kc++) {
        short8 bk = *(const short8*)&Kl[p][krow * 128 + (((kc * 4 + quad) ^ (c16 & 7)) << 3)];
        s0 = __builtin_amdgcn_mfma_f32_16x16x32_bf16(aq[kc], bk, s0, 0, 0, 0);
      }
      __builtin_amdgcn_s_setprio(0);
#pragma unroll
      for (int r = 0; r < 4; r++) {
        float p0 = __expf(s0[r]);
        lacc[r] += p0;
        // swizzled P store: element (row, col) -> row*64 + ((col>>3 ^ row&7)<<3) + (col&7)
        const int rlo = w * 16 + quad * 4 + r;
        const int sw = ((((st * 2) + (c16 >> 3)) ^ (rlo & 7)) << 3) | (c16 & 7);
        Pl[rlo * 64 + sw] = f2bf(p0);
      }
    }
    __syncthreads();                    // P visible; V(t) + K(t+1) DMA drained

    // ---- PV: 32 rows x 64 dv per wave ----
#pragma unroll
    for (int tc = 0; tc < 2; tc++) {
      short8 ap[2];
#pragma unroll
      for (int mt = 0; mt < 2; mt++) {
        const int row = prow0 + mt * 16 + c16;          // row&7 == c16&7
        ap[mt] = *(const short8*)&Pl[row * 64 + (((tc * 4 + quad) ^ (c16 & 7)) << 3)];
      }
      __builtin_amdgcn_s_setprio(1);
#pragma unroll
      for (int nt = 0; nt < 4; nt++) {
        const int dv = dv0 + nt * 16 + c16;             // dv&7 == c16&7
        short8 bv = *(const short8*)&Vt[dv * 64 + (((tc * 4 + quad) ^ (c16 & 7)) << 3)];
#pragma unroll
        for (int mt = 0; mt < 2; mt++)
          o[mt][nt] = __builtin_amdgcn_mfma_f32_16x16x32_bf16(ap[mt], bv, o[mt][nt], 0, 0, 0);
      }
      __builtin_amdgcn_s_setprio(0);
    }
  }

  // final l reduction (QK rows of this wave) -> Ls (aliased over Pl, now dead)
  __syncthreads();                      // all waves past last PV reads of Pl
#pragma unroll
  for (int r = 0; r < 4; r++) {
    float l = lacc[r];
    l += __shfl_xor(l, 1);
    l += __shfl_xor(l, 2);
    l += __shfl_xor(l, 4);
    l += __shfl_xor(l, 8);
    if (c16 == 0) Ls[w * 16 + quad * 4 + r] = l;
  }
  __syncthreads();

  // epilogue: write O / l
#pragma unroll
  for (int mt = 0; mt < 2; mt++) {
#pragma unroll
    for (int r = 0; r < 4; r++) {
      const float inv = 1.f / Ls[prow0 + mt * 16 + quad * 4 + r];
      const size_t row = (size_t)qb * 128 + prow0 + mt * 16 + quad * 4 + r;
#pragma unroll
      for (int nt = 0; nt < 4; nt++)
        Z[row * 16384 + hh * 128 + dv0 + nt * 16 + c16] = f2bf(o[mt][nt][r] * inv);
    }
  }
}

// ---------- host ----------
extern "C" void kernel_launch(void* const* d_in, const int* in_sizes, int n_in,
                              void* d_out, int out_size, void* d_ws, size_t ws_size,
                              hipStream_t stream) {
  (void)in_sizes; (void)n_in; (void)out_size; (void)ws_size;
  const float* x        = (const float*)d_in[0];
  const float* gamma_in = (const float*)d_in[1];
  const float* Wq_w     = (const float*)d_in[2];
  const float* Wq_b     = (const float*)d_in[3];
  const float* Wkv_w    = (const float*)d_in[4];
  const float* Wkv_b    = (const float*)d_in[5];
  const float* gamma_z  = (const float*)d_in[6];
  const float* W1       = (const float*)d_in[7];
  const float* b1       = (const float*)d_in[8];
  const float* W2       = (const float*)d_in[9];
  const float* b2       = (const float*)d_in[10];
  float* out = (float*)d_out;

  char* ws = (char*)d_ws;
  size_t off = 0;
  auto alloc = [&](size_t bytes) {
    void* p = ws + off;
    off += (bytes + 255) & ~(size_t)255;
    return p;
  };
  ushort* xn   = (ushort*)alloc((size_t)1024 * 1024 * 2);    //  2 MB
  ushort* Wqb  = (ushort*)alloc((size_t)16384 * 1024 * 2);   // 32 MB (Wkvb contiguous after)
  ushort* Wkvb = (ushort*)alloc((size_t)2048 * 1024 * 2);    //  4 MB
  ushort* W1b  = (ushort*)alloc((size_t)2048 * 16384 * 2);   // 64 MB
  ushort* W2b  = (ushort*)alloc((size_t)1024 * 2048 * 2);    //  4 MB
  ushort* Qb   = (ushort*)alloc((size_t)1024 * 16384 * 2);   // 32 MB
  ushort* KVb  = (ushort*)alloc((size_t)1024 * 2048 * 2);    //  4 MB
  // time-disjoint aliases (stream-ordered):
  ushort* Zb   = Wqb;            // attention out (32 MB) — after QKV-GEMM reads Wqb
  ushort* VTb  = Wkvb;           // V^T (4 MB) — after QKV-GEMM reads Wkvb
  ushort* ZN   = Qb;             // rmsnorm(z) — after attention reads Qb
  float*  h1f  = (float*)Wqb;    // W1 partials: 4 planes x 8 MB — after rmsnorm reads Zb
  ushort* H1   = Wkvb;           // silu(h1) bf16 (4 MB) — after attention reads VTb
  float*  outf = (float*)Qb;     // W2 partials: 4 planes x 4 MB — after W1-GEMM reads ZN

  cvt_all<<<16384 + 2048 + 32768 + 2048, 256, 0, stream>>>(
      Wq_w, Wqb, 16384, Wkv_w, Wkvb, 2048, W1, W1b, 32768, W2, W2b);

  rmsnorm_f32<<<1024, 256, 0, stream>>>(x, gamma_in, xn, 1024, 32.0f);

  // fused Q+KV projection; Q pre-scaled by 1/sqrt(128)
  { dim3 g(8, 144, 1);
    gemm3<2, 0, 1><<<g, 256, 0, stream>>>(xn, Wqb, Wq_b, Wkv_b, Qb, KVb,
                                          1024, 18432, 1024, 1024, 0.08838834764831845f); }

  { dim3 g(16, 8); vtrans<<<g, 256, 0, stream>>>(KVb, VTb); }

  attn9<<<1024, 512, 0, stream>>>(Qb, KVb, VTb, Zb);

  rmsnorm_bf16<<<1024, 256, 0, stream>>>(Zb, gamma_z, ZN, 16384, 128.0f);

  // W1: split-K=4 disjoint fp32 planes, then sum+bias+SiLU -> bf16
  { dim3 g(8, 16, 4);
    gemm3<1, 0, 0><<<g, 256, 0, stream>>>(ZN, W1b, b1, nullptr, h1f, nullptr,
                                          1024, 2048, 16384, 4096, 0.f); }
  epi_sum_silu<4, 1><<<2048, 256, 0, stream>>>(h1f, b1, H1, 2048, 1024 * 2048 / 4,
                                               (size_t)1024 * 2048 / 4);

  // W2: split-K=4 planes, then sum+bias+SiLU -> fp32 out
  { dim3 g(8, 8, 4);
    gemm3<1, 0, 0><<<g, 256, 0, stream>>>(H1, W2b, b2, nullptr, outf, nullptr,
                                          1024, 1024, 2048, 512, 0.f); }
  epi_sum_silu<4, 0><<<1024, 256, 0, stream>>>(outf, b2, out, 1024, 1024 * 1024 / 4,
                                               (size_t)1024 * 1024 / 4);
}

// Round 5
// 564.820 us; speedup vs baseline: 1.4966x; 1.0062x over previous
//
#include <hip/hip_runtime.h>
#include <hip/hip_bf16.h>
#include <math.h>

typedef __attribute__((ext_vector_type(8))) short short8;   // 8 x bf16 (MFMA frag)
typedef __attribute__((ext_vector_type(4))) float floatx4;  // MFMA accumulator

__device__ __forceinline__ ushort f2bf(float f) {
  __hip_bfloat16 h = __float2bfloat16(f);
  return *reinterpret_cast<ushort*>(&h);
}
__device__ __forceinline__ float bf2f(ushort u) {
  union { unsigned int i; float f; } c; c.i = ((unsigned)u) << 16; return c.f;
}

// async global->LDS 16B DMA (dest = wave-uniform base + lane*16)
__device__ __forceinline__ void lds_dma16(const void* g, void* l) {
  __builtin_amdgcn_global_load_lds((const __attribute__((address_space(1))) void*)g,
                                   (__attribute__((address_space(3))) void*)l, 16, 0, 0);
}

// ---------- fused fp32 -> bf16 conversion for all four weights ----------
__global__ __launch_bounds__(256) void cvt_all(const float* __restrict__ p0, ushort* __restrict__ o0, int b0,
                                               const float* __restrict__ p1, ushort* __restrict__ o1, int b1,
                                               const float* __restrict__ p2, ushort* __restrict__ o2, int b2,
                                               const float* __restrict__ p3, ushort* __restrict__ o3) {
  int b = blockIdx.x;
  const float* in; ushort* out; int base;
  if (b < b0)            { in = p0; out = o0; base = 0; }
  else if (b < b0 + b1)  { in = p1; out = o1; base = b0; }
  else if (b < b0 + b1 + b2) { in = p2; out = o2; base = b0 + b1; }
  else                   { in = p3; out = o3; base = b0 + b1 + b2; }
  int i = (b - base) * 256 + threadIdx.x;
  float4 v = ((const float4*)in)[i];
  ushort4 o;
  o.x = f2bf(v.x); o.y = f2bf(v.y); o.z = f2bf(v.z); o.w = f2bf(v.w);
  ((ushort4*)out)[i] = o;
}

// ---------- RMSNorm fp32 -> bf16 ----------
__global__ __launch_bounds__(256) void rmsnorm_f32(const float* __restrict__ x,
                                                   const float* __restrict__ gamma,
                                                   ushort* __restrict__ y, int D, float sqrtD) {
  const int row = blockIdx.x;
  const float* xr = x + (size_t)row * D;
  float ss = 0.f;
  for (int i = threadIdx.x * 4; i < D; i += 1024) {
    float4 v = *(const float4*)&xr[i];
    ss += v.x * v.x + v.y * v.y + v.z * v.z + v.w * v.w;
  }
#pragma unroll
  for (int off = 1; off < 64; off <<= 1) ss += __shfl_xor(ss, off);
  __shared__ float red[4];
  if ((threadIdx.x & 63) == 0) red[threadIdx.x >> 6] = ss;
  __syncthreads();
  ss = red[0] + red[1] + red[2] + red[3];
  const float sc = sqrtD / fmaxf(sqrtf(ss), 1e-12f);
  for (int i = threadIdx.x * 4; i < D; i += 1024) {
    float4 v = *(const float4*)&xr[i];
    ushort4 o;
    o.x = f2bf(v.x * sc * gamma[i]);
    o.y = f2bf(v.y * sc * gamma[i + 1]);
    o.z = f2bf(v.z * sc * gamma[i + 2]);
    o.w = f2bf(v.w * sc * gamma[i + 3]);
    *(ushort4*)&y[(size_t)row * D + i] = o;
  }
}

// ---------- RMSNorm bf16 -> bf16, single-pass (row held in registers) ----------
// D must be 16384 (call-site fixed): 256 thr x 8 x short8 = whole row, 32 VGPR.
__global__ __launch_bounds__(256) void rmsnorm_bf16(const ushort* __restrict__ x,
                                                    const float* __restrict__ gamma,
                                                    ushort* __restrict__ y, int D, float sqrtD) {
  const int row = blockIdx.x;
  const ushort* xr = x + (size_t)row * D;
  short8 v[8];
  float ss = 0.f;
#pragma unroll
  for (int j = 0; j < 8; j++) {
    v[j] = *(const short8*)&xr[threadIdx.x * 8 + j * 2048];
#pragma unroll
    for (int e = 0; e < 8; e++) { float f = bf2f((ushort)v[j][e]); ss += f * f; }
  }
#pragma unroll
  for (int off = 1; off < 64; off <<= 1) ss += __shfl_xor(ss, off);
  __shared__ float red[4];
  if ((threadIdx.x & 63) == 0) red[threadIdx.x >> 6] = ss;
  __syncthreads();
  ss = red[0] + red[1] + red[2] + red[3];
  const float sc = sqrtD / fmaxf(sqrtf(ss), 1e-12f);
#pragma unroll
  for (int j = 0; j < 8; j++) {
    const int i = threadIdx.x * 8 + j * 2048;
    short8 ov;
#pragma unroll
    for (int e = 0; e < 8; e++) ov[e] = (short)f2bf(bf2f((ushort)v[j][e]) * sc * gamma[i + e]);
    *(short8*)&y[(size_t)row * D + i] = ov;
  }
}

// ---------- GEMM v4: 128x128 tile, BK=64, global_load_lds + XOR swizzle ----------
// XCD-chunked block swizzle: hardware assigns XCD = dispatch_linear % 8; we remap
// so each XCD owns a contiguous ni-range (B col-panels L2-resident per XCD).
// Requires gridDim.x == 8 and (gridDim.x*gridDim.y) % 8 == 0 (all call sites).
template <int EPI, int ACT, int OUTBF16>
__global__ __launch_bounds__(256, 3) void gemm3(const ushort* __restrict__ A,
                                                const ushort* __restrict__ B,
                                                const float* __restrict__ bias,
                                                const float* __restrict__ bias2,
                                                void* __restrict__ C1,
                                                void* __restrict__ C2,
                                                int M, int N, int K, int Ksplit, float scale) {
  __shared__ ushort As[128 * 64];
  __shared__ ushort Bs[128 * 64];
  const int tid = threadIdx.x;
  const int wave = tid >> 6;
  const int lane = tid & 63;
  const int c16 = lane & 15;
  const int quad = lane >> 4;
  const int wm = wave >> 1;
  const int wn = wave & 1;
  // --- XCD swizzle (bijective per z-plane; plane sizes are multiples of 8) ---
  const int P = gridDim.x * gridDim.y;
  const int lin = blockIdx.x + gridDim.x * blockIdx.y;
  const int lin2 = (lin & 7) * (P >> 3) + (lin >> 3);
  const int bx = lin2 & 7;              // gridDim.x == 8 at every call site
  const int by = lin2 >> 3;
  const size_t m0 = (size_t)bx * 128;
  const size_t n0 = (size_t)by * 128;
  const int kbeg = blockIdx.z * Ksplit;
  const int kend = kbeg + Ksplit;

  const int rsub = lane >> 3;
  const int csw = (lane & 7) ^ rsub;

  const floatx4 zero = {0.f, 0.f, 0.f, 0.f};
  floatx4 acc[4][4];
#pragma unroll
  for (int a = 0; a < 4; a++)
#pragma unroll
    for (int b = 0; b < 4; b++) acc[a][b] = zero;

  for (int k0 = kbeg; k0 < kend; k0 += 64) {
    __syncthreads();
#pragma unroll
    for (int i = 0; i < 4; i++) {
      const int j = wave * 4 + i;
      const int r = j * 8 + rsub;
      lds_dma16(&A[(m0 + r) * K + k0 + csw * 8], (void*)(As + j * 512));
      lds_dma16(&B[(n0 + r) * K + k0 + csw * 8], (void*)(Bs + j * 512));
    }
    __syncthreads();
#pragma unroll
    for (int kc = 0; kc < 2; kc++) {
      short8 af[4], bf4[4];
#pragma unroll
      for (int mt = 0; mt < 4; mt++) {
        const int row = wm * 64 + mt * 16 + c16;
        af[mt] = *(const short8*)&As[row * 64 + (((kc * 4 + quad) ^ (row & 7)) << 3)];
      }
#pragma unroll
      for (int nt = 0; nt < 4; nt++) {
        const int row = wn * 64 + nt * 16 + c16;
        bf4[nt] = *(const short8*)&Bs[row * 64 + (((kc * 4 + quad) ^ (row & 7)) << 3)];
      }
#pragma unroll
      for (int mt = 0; mt < 4; mt++)
#pragma unroll
        for (int nt = 0; nt < 4; nt++)
          acc[mt][nt] = __builtin_amdgcn_mfma_f32_16x16x32_bf16(af[mt], bf4[nt], acc[mt][nt], 0, 0, 0);
    }
  }

#pragma unroll
  for (int mt = 0; mt < 4; mt++) {
#pragma unroll
    for (int nt = 0; nt < 4; nt++) {
      const size_t col = n0 + wn * 64 + nt * 16 + c16;
      const size_t row0 = m0 + wm * 64 + mt * 16 + quad * 4;
      if (EPI == 0) {
        const float bv = bias[col];
#pragma unroll
        for (int r = 0; r < 4; r++) {
          float v = acc[mt][nt][r] + bv;
          if (ACT) v = v / (1.f + __expf(-v));
          if (OUTBF16) ((ushort*)C1)[(row0 + r) * N + col] = f2bf(v);
          else         ((float*)C1)[(row0 + r) * N + col] = v;
        }
      } else if (EPI == 1) {
        float* plane = (float*)C1 + (size_t)blockIdx.z * M * N;
#pragma unroll
        for (int r = 0; r < 4; r++)
          plane[(row0 + r) * N + col] = acc[mt][nt][r];
      } else {
        if (col < 16384) {
          const float bv = bias[col];
#pragma unroll
          for (int r = 0; r < 4; r++)
            ((ushort*)C1)[(row0 + r) * 16384 + col] = f2bf((acc[mt][nt][r] + bv) * scale);
        } else {
          const size_t ckv = col - 16384;
          const float bv = bias2[ckv];
#pragma unroll
          for (int r = 0; r < 4; r++)
            ((ushort*)C2)[(row0 + r) * 2048 + ckv] = f2bf(acc[mt][nt][r] + bv);
        }
      }
    }
  }
}

// ---------- split-K reduce + bias + SiLU epilogue ----------
template <int NZ, int OUTBF16>
__global__ __launch_bounds__(256) void epi_sum_silu(const float* __restrict__ accb,
                                                    const float* __restrict__ bias,
                                                    void* __restrict__ outp, int N, int n4,
                                                    size_t plane4) {
  int i = blockIdx.x * 256 + threadIdx.x;
  if (i >= n4) return;
  float4 v = ((const float4*)accb)[i];
#pragma unroll
  for (int z = 1; z < NZ; z++) {
    float4 p = ((const float4*)accb)[i + z * plane4];
    v.x += p.x; v.y += p.y; v.z += p.z; v.w += p.w;
  }
  const float4 b = *(const float4*)&bias[(i * 4) % N];
  v.x += b.x; v.y += b.y; v.z += b.z; v.w += b.w;
  v.x = v.x / (1.f + __expf(-v.x));
  v.y = v.y / (1.f + __expf(-v.y));
  v.z = v.z / (1.f + __expf(-v.z));
  v.w = v.w / (1.f + __expf(-v.w));
  if (OUTBF16) {
    ushort4 o; o.x = f2bf(v.x); o.y = f2bf(v.y); o.z = f2bf(v.z); o.w = f2bf(v.w);
    ((ushort4*)outp)[i] = o;
  } else {
    ((float4*)outp)[i] = v;
  }
}

// ---------- V transpose: KV(S,2048) -> VT(G,128,S) ----------
__global__ __launch_bounds__(256) void vtrans(const ushort* __restrict__ KV,
                                              ushort* __restrict__ VT) {
  __shared__ ushort Vl[64 * 138];
  const int tid = threadIdx.x;
  const int t0 = blockIdx.x * 64;
  const int g = blockIdx.y;
#pragma unroll
  for (int i = 0; i < 16; i++) {
    int idx = tid + i * 256;
    int r = idx >> 6, dc = idx & 63;
    *(uint*)&Vl[r * 138 + dc * 2] =
        *(const uint*)&KV[(size_t)(t0 + r) * 2048 + 1024 + g * 128 + dc * 2];
  }
  __syncthreads();
#pragma unroll
  for (int i = 0; i < 4; i++) {
    int idx = tid + i * 256;
    int dv = idx >> 3, tch = idx & 7;
    short8 o;
#pragma unroll
    for (int j = 0; j < 8; j++) o[j] = (short)Vl[(tch * 8 + j) * 138 + dv];
    *(short8*)&VT[(size_t)g * 131072 + (size_t)dv * 1024 + t0 + tch * 8] = o;
  }
}

// ---------- Flash attention v9: slim waves for 2 blocks/CU ----------
// Grid 1024 x 512 threads. Block covers 128 Q rows of head hh: hh = b>>3, qb = b&7.
// Per wave: QK 16 rows (aq[4]=16 regs), PV 32 rows x 64 dv (o[2][4]=32 acc).
// LDS: Kl[2] 32K + Vt 16K + Pl[128][64] 16K = 64 KiB -> 2 blocks/CU, 16 waves/CU.
// XCD swizzle: 1024 blocks = 8 XCD x 128; one KV-group per XCD.
__global__ __launch_bounds__(512, 4) void attn9(const ushort* __restrict__ Q,
                                                const ushort* __restrict__ KV,
                                                const ushort* __restrict__ VT,
                                                ushort* __restrict__ Z) {
  __shared__ ushort Kl[2][64 * 128];   // [T][dq] unpadded, XOR chunk swizzle
  __shared__ ushort Vt[128 * 64];      // [dv][T] unpadded, XOR chunk swizzle (single buf)
  __shared__ ushort Pl[128 * 64];      // [row][T] ld=64, XOR chunk swizzle
  float* Ls = (float*)Pl;              // [128] aliased; valid after last PV
  const int tid = threadIdx.x;
  const int w = tid >> 6;              // 0..7
  const int lane = tid & 63;
  const int c16 = lane & 15;
  const int quad = lane >> 4;
  // XCD-aware swizzle: 1024 blocks over 8 XCDs, contiguous 128-block chunk per XCD
  const int b = (blockIdx.x & 7) * 128 + (blockIdx.x >> 3);
  const int hh = b >> 3;               // head 0..127
  const int qb = b & 7;                // 128-row chunk of S=1024
  const int g = hh >> 4;
  const int prow0 = (w & 3) * 32;      // PV rows (block-local)
  const int dv0 = (w >> 2) * 64;       // PV dv half

  const ushort* Kg = KV + (size_t)g * 128;
  const ushort* Vg = VT + (size_t)g * 131072;

  // QK fragments: rows [qb*128 + w*16, +16)
  short8 aq[4];
#pragma unroll
  for (int kc = 0; kc < 4; kc++)
    aq[kc] = *(const short8*)&Q[(size_t)(qb * 128 + w * 16 + c16) * 16384 +
                                hh * 128 + kc * 32 + quad * 8];

  const floatx4 zero = {0.f, 0.f, 0.f, 0.f};
  floatx4 o[2][4];
  float lacc[4];
#pragma unroll
  for (int mt = 0; mt < 2; mt++)
#pragma unroll
    for (int nt = 0; nt < 4; nt++) o[mt][nt] = zero;
#pragma unroll
  for (int r = 0; r < 4; r++) lacc[r] = 0.f;

  // staging geometry (per wave: 2 K-issues + 2 V-issues, 16B chunks)
  const int kr16 = lane >> 4;          // K: row-within-issue
  const int kc16 = lane & 15;          // K: chunk pos (16 chunks/row)
  const int vr8 = lane >> 3;           // V: row-within-issue
  const int vc8 = lane & 7;            // V: chunk pos (8 chunks/row)

  auto stageK = [&](int buf, int t0) {
#pragma unroll
    for (int i = 0; i < 2; i++) {
      int krow = w * 8 + i * 4 + kr16;
      int kcs = kc16 ^ (krow & 7);
      lds_dma16(&Kg[(size_t)(t0 + krow) * 2048 + kcs * 8],
                (void*)(&Kl[buf][w * 1024 + i * 512]));
    }
  };
  auto stageV = [&](int t0) {
#pragma unroll
    for (int i = 0; i < 2; i++) {
      int vrow = w * 16 + i * 8 + vr8;
      int vcs = vc8 ^ (vrow & 7);
      lds_dma16(&Vg[(size_t)vrow * 1024 + t0 + vcs * 8],
                (void*)(&Vt[w * 1024 + i * 512]));
    }
  };

  stageK(0, 0);  // prologue: K tile 0

  for (int t = 0; t < 16; t++) {
    const int p = t & 1;
    __syncthreads();                    // K(t) staged; PV(t-1) done -> Vt, Pl free
    if (t < 15) stageK(p ^ 1, (t + 1) * 64);
    stageV(t * 64);                     // V(t) -> single buffer; drained at barrier2

    // ---- QK: 16 rows x 64 T per wave ----
#pragma unroll
    for (int st = 0; st < 4; st++) {
      floatx4 s0 = zero;
      const int krow = st * 16 + c16;
      __builtin_amdgcn_s_setprio(1);
#pragma unroll
      for (int kc = 0; kc < 4; kc++) {
        short8 bk = *(const short8*)&Kl[p][krow * 128 + (((kc * 4 + quad) ^ (c16 & 7)) << 3)];
        s0 = __builtin_amdgcn_mfma_f32_16x16x32_bf16(aq[kc], bk, s0, 0, 0, 0);
      }
      __builtin_amdgcn_s_setprio(0);
#pragma unroll
      for (int r = 0; r < 4; r++) {
        float p0 = __expf(s0[r]);
        lacc[r] += p0;
        // swizzled P store: element (row, col) -> row*64 + ((col>>3 ^ row&7)<<3) + (col&7)
        const int rlo = w * 16 + quad * 4 + r;
        const int sw = ((((st * 2) + (c16 >> 3)) ^ (rlo & 7)) << 3) | (c16 & 7);
        Pl[rlo * 64 + sw] = f2bf(p0);
      }
    }
    __syncthreads();                    // P visible; V(t) + K(t+1) DMA drained

    // ---- PV: 32 rows x 64 dv per wave ----
#pragma unroll
    for (int tc = 0; tc < 2; tc++) {
      short8 ap[2];
#pragma unroll
      for (int mt = 0; mt < 2; mt++) {
        const int row = prow0 + mt * 16 + c16;          // row&7 == c16&7
        ap[mt] = *(const short8*)&Pl[row * 64 + (((tc * 4 + quad) ^ (c16 & 7)) << 3)];
      }
      __builtin_amdgcn_s_setprio(1);
#pragma unroll
      for (int nt = 0; nt < 4; nt++) {
        const int dv = dv0 + nt * 16 + c16;             // dv&7 == c16&7
        short8 bv = *(const short8*)&Vt[dv * 64 + (((tc * 4 + quad) ^ (c16 & 7)) << 3)];
#pragma unroll
        for (int mt = 0; mt < 2; mt++)
          o[mt][nt] = __builtin_amdgcn_mfma_f32_16x16x32_bf16(ap[mt], bv, o[mt][nt], 0, 0, 0);
      }
      __builtin_amdgcn_s_setprio(0);
    }
  }

  // final l reduction (QK rows of this wave) -> Ls (aliased over Pl, now dead)
  __syncthreads();                      // all waves past last PV reads of Pl
#pragma unroll
  for (int r = 0; r < 4; r++) {
    float l = lacc[r];
    l += __shfl_xor(l, 1);
    l += __shfl_xor(l, 2);
    l += __shfl_xor(l, 4);
    l += __shfl_xor(l, 8);
    if (c16 == 0) Ls[w * 16 + quad * 4 + r] = l;
  }
  __syncthreads();

  // epilogue: write O / l
#pragma unroll
  for (int mt = 0; mt < 2; mt++) {
#pragma unroll
    for (int r = 0; r < 4; r++) {
      const float inv = 1.f / Ls[prow0 + mt * 16 + quad * 4 + r];
      const size_t row = (size_t)qb * 128 + prow0 + mt * 16 + quad * 4 + r;
#pragma unroll
      for (int nt = 0; nt < 4; nt++)
        Z[row * 16384 + hh * 128 + dv0 + nt * 16 + c16] = f2bf(o[mt][nt][r] * inv);
    }
  }
}

// ---------- host ----------
extern "C" void kernel_launch(void* const* d_in, const int* in_sizes, int n_in,
                              void* d_out, int out_size, void* d_ws, size_t ws_size,
                              hipStream_t stream) {
  (void)in_sizes; (void)n_in; (void)out_size; (void)ws_size;
  const float* x        = (const float*)d_in[0];
  const float* gamma_in = (const float*)d_in[1];
  const float* Wq_w     = (const float*)d_in[2];
  const float* Wq_b     = (const float*)d_in[3];
  const float* Wkv_w    = (const float*)d_in[4];
  const float* Wkv_b    = (const float*)d_in[5];
  const float* gamma_z  = (const float*)d_in[6];
  const float* W1       = (const float*)d_in[7];
  const float* b1       = (const float*)d_in[8];
  const float* W2       = (const float*)d_in[9];
  const float* b2       = (const float*)d_in[10];
  float* out = (float*)d_out;

  char* ws = (char*)d_ws;
  size_t off = 0;
  auto alloc = [&](size_t bytes) {
    void* p = ws + off;
    off += (bytes + 255) & ~(size_t)255;
    return p;
  };
  ushort* xn   = (ushort*)alloc((size_t)1024 * 1024 * 2);    //  2 MB
  ushort* Wqb  = (ushort*)alloc((size_t)16384 * 1024 * 2);   // 32 MB (Wkvb contiguous after)
  ushort* Wkvb = (ushort*)alloc((size_t)2048 * 1024 * 2);    //  4 MB
  ushort* W1b  = (ushort*)alloc((size_t)2048 * 16384 * 2);   // 64 MB
  ushort* W2b  = (ushort*)alloc((size_t)1024 * 2048 * 2);    //  4 MB
  ushort* Qb   = (ushort*)alloc((size_t)1024 * 16384 * 2);   // 32 MB
  ushort* KVb  = (ushort*)alloc((size_t)1024 * 2048 * 2);    //  4 MB
  // time-disjoint aliases (stream-ordered):
  ushort* Zb   = Wqb;            // attention out (32 MB) — after QKV-GEMM reads Wqb
  ushort* VTb  = Wkvb;           // V^T (4 MB) — after QKV-GEMM reads Wkvb
  ushort* ZN   = Qb;             // rmsnorm(z) — after attention reads Qb
  float*  h1f  = (float*)Wqb;    // W1 partials: 4 planes x 8 MB — after rmsnorm reads Zb
  ushort* H1   = Wkvb;           // silu(h1) bf16 (4 MB) — after attention reads VTb
  float*  outf = (float*)Qb;     // W2 partials: 4 planes x 4 MB — after W1-GEMM reads ZN

  cvt_all<<<16384 + 2048 + 32768 + 2048, 256, 0, stream>>>(
      Wq_w, Wqb, 16384, Wkv_w, Wkvb, 2048, W1, W1b, 32768, W2, W2b);

  rmsnorm_f32<<<1024, 256, 0, stream>>>(x, gamma_in, xn, 1024, 32.0f);

  // fused Q+KV projection; Q pre-scaled by 1/sqrt(128)
  { dim3 g(8, 144, 1);
    gemm3<2, 0, 1><<<g, 256, 0, stream>>>(xn, Wqb, Wq_b, Wkv_b, Qb, KVb,
                                          1024, 18432, 1024, 1024, 0.08838834764831845f); }

  { dim3 g(16, 8); vtrans<<<g, 256, 0, stream>>>(KVb, VTb); }

  attn9<<<1024, 512, 0, stream>>>(Qb, KVb, VTb, Zb);

  rmsnorm_bf16<<<1024, 256, 0, stream>>>(Zb, gamma_z, ZN, 16384, 128.0f);

  // W1: split-K=4 disjoint fp32 planes, then sum+bias+SiLU -> bf16
  { dim3 g(8, 16, 4);
    gemm3<1, 0, 0><<<g, 256, 0, stream>>>(ZN, W1b, b1, nullptr, h1f, nullptr,
                                          1024, 2048, 16384, 4096, 0.f); }
  epi_sum_silu<4, 1><<<2048, 256, 0, stream>>>(h1f, b1, H1, 2048, 1024 * 2048 / 4,
                                               (size_t)1024 * 2048 / 4);

  // W2: split-K=4 planes, then sum+bias+SiLU -> fp32 out
  { dim3 g(8, 8, 4);
    gemm3<1, 0, 0><<<g, 256, 0, stream>>>(H1, W2b, b2, nullptr, outf, nullptr,
                                          1024, 1024, 2048, 512, 0.f); }
  epi_sum_silu<4, 0><<<1024, 256, 0, stream>>>(outf, b2, out, 1024, 1024 * 1024 / 4,
                                               (size_t)1024 * 1024 / 4);
}